// Round 1
// baseline (711.789 us; speedup 1.0000x reference)
//
#include <hip/hip_runtime.h>

// Problem constants: N=2, S=2048, E=2048, H=16, Dk=128
// M_total = N*S = 4096, K = E = 2048, N_out = E = 2048

typedef __attribute__((ext_vector_type(8))) short bf16x8;
typedef __attribute__((ext_vector_type(4))) float f32x4;

__device__ __forceinline__ unsigned short f2bf(float f) {
    unsigned u = __float_as_uint(f);
    u += 0x7fffu + ((u >> 16) & 1u);   // round-to-nearest-even
    return (unsigned short)(u >> 16);
}

template<typename T>
__device__ __forceinline__ bf16x8 load8bf(const T* p) {
    if constexpr (sizeof(T) == 4) {
        const float4* q = (const float4*)p;
        float4 a = q[0], b = q[1];
        bf16x8 r;
        r[0] = (short)f2bf(a.x); r[1] = (short)f2bf(a.y);
        r[2] = (short)f2bf(a.z); r[3] = (short)f2bf(a.w);
        r[4] = (short)f2bf(b.x); r[5] = (short)f2bf(b.y);
        r[6] = (short)f2bf(b.z); r[7] = (short)f2bf(b.w);
        return r;
    } else {
        return *(const bf16x8*)p;
    }
}

// ---------------------------------------------------------------------------
// GEMM: C[m][j] = sum_k A[m][k] * B[j][k] + bias[j]
// A: 4096 x 2048 row-major (fp32 or bf16-as-ushort), B: 2048 x 2048 fp32 row-major.
// MODE 0: store bf16 head-split   [n][h][s][d]   (Q, K)
// MODE 2: store bf16 head-split-T [n][h][d][s]   (V)
// MODE 1: store fp32 flat         [m][j]          (final output)
// 256 threads = 4 waves (2x2), each wave 64x64 output, BK=64.
// ---------------------------------------------------------------------------
template<typename TA, int MODE>
__global__ __launch_bounds__(256, 2) void gemm_bt(
    const TA* __restrict__ A, const float* __restrict__ B,
    const float* __restrict__ bias, void* __restrict__ Cout)
{
    const int K = 2048;
    __shared__ unsigned short As[128 * 64];
    __shared__ unsigned short Bs[128 * 64];

    const int tid  = threadIdx.x;
    const int lane = tid & 63;
    const int w    = tid >> 6;
    const int wr   = w >> 1, wc = w & 1;
    const int m0   = (blockIdx.x & 31) << 7;   // 32 m-tiles
    const int n0   = (blockIdx.x >> 5) << 7;   // 16 n-tiles

    f32x4 acc[4][4];
    #pragma unroll
    for (int i = 0; i < 4; ++i)
        #pragma unroll
        for (int j = 0; j < 4; ++j) { f32x4 z = {0.f,0.f,0.f,0.f}; acc[i][j] = z; }

    const int g  = tid & 7;    // 8-elem chunk within a 64-wide row
    const int r0 = tid >> 3;   // 0..31

    for (int kt = 0; kt < 32; ++kt) {
        const int k0 = kt * 64;
        #pragma unroll
        for (int i = 0; i < 4; ++i) {
            int row = i * 32 + r0;
            bf16x8 av = load8bf(A + (size_t)(m0 + row) * K + k0 + g * 8);
            *(bf16x8*)&As[row * 64 + ((g * 8) ^ ((row & 7) << 3))] = av;
            bf16x8 bv = load8bf(B + (size_t)(n0 + row) * K + k0 + g * 8);
            *(bf16x8*)&Bs[row * 64 + ((g * 8) ^ ((row & 7) << 3))] = bv;
        }
        __syncthreads();
        #pragma unroll
        for (int kk = 0; kk < 2; ++kk) {
            const int kc = kk * 32 + (lane >> 4) * 8;
            bf16x8 af[4], bfr[4];
            #pragma unroll
            for (int t = 0; t < 4; ++t) {
                int ar = wr * 64 + t * 16 + (lane & 15);
                af[t]  = *(const bf16x8*)&As[ar * 64 + (kc ^ ((ar & 7) << 3))];
                int br = wc * 64 + t * 16 + (lane & 15);
                bfr[t] = *(const bf16x8*)&Bs[br * 64 + (kc ^ ((br & 7) << 3))];
            }
            #pragma unroll
            for (int tm = 0; tm < 4; ++tm)
                #pragma unroll
                for (int tn = 0; tn < 4; ++tn)
                    acc[tm][tn] = __builtin_amdgcn_mfma_f32_16x16x32_bf16(
                        af[tm], bfr[tn], acc[tm][tn], 0, 0, 0);
        }
        __syncthreads();
    }

    // epilogue: C/D layout col = lane&15, row = (lane>>4)*4 + reg  [m89-verified]
    const int lr = lane >> 4, lc = lane & 15;
    #pragma unroll
    for (int tn = 0; tn < 4; ++tn) {
        int col = n0 + wc * 64 + tn * 16 + lc;
        float bv = bias[col];
        #pragma unroll
        for (int tm = 0; tm < 4; ++tm) {
            #pragma unroll
            for (int r = 0; r < 4; ++r) {
                int row = m0 + wr * 64 + tm * 16 + lr * 4 + r;
                float v = acc[tm][tn][r] + bv;
                if constexpr (MODE == 1) {
                    ((float*)Cout)[(size_t)row * 2048 + col] = v;
                } else if constexpr (MODE == 0) {
                    int nb = row >> 11, s = row & 2047, h = col >> 7, d = col & 127;
                    ((unsigned short*)Cout)[(((size_t)(nb * 16 + h)) * 2048 + s) * 128 + d] = f2bf(v);
                } else {
                    int nb = row >> 11, s = row & 2047, h = col >> 7, d = col & 127;
                    ((unsigned short*)Cout)[(((size_t)(nb * 16 + h)) * 128 + d) * 2048 + s] = f2bf(v);
                }
            }
        }
    }
}

// ---------------------------------------------------------------------------
// Flash attention forward. Grid: N*H*(S/64) = 1024 blocks, 256 threads (4 waves).
// Each block: one (n,h), 64 Q-rows; wave w owns rows w*16..w*16+15.
// Q,K: [n][h][s][d] bf16.  Vt: [n][h][d][s] bf16.  O out: [n][h][s][d] bf16.
// ---------------------------------------------------------------------------
__global__ __launch_bounds__(256, 2) void attn_fwd(
    const unsigned short* __restrict__ Qb, const unsigned short* __restrict__ Kb,
    const unsigned short* __restrict__ Vtb, unsigned short* __restrict__ Ob)
{
    __shared__ unsigned short Qs[64 * 128];
    __shared__ unsigned short Ks[64 * 128];
    __shared__ unsigned short Vts[128 * 64];
    __shared__ unsigned short Ps[64 * 64];

    const int tid = threadIdx.x, lane = tid & 63, w = tid >> 6;
    const int bx = blockIdx.x;
    const int qt = bx & 31, h = (bx >> 5) & 15, n = bx >> 9;
    const size_t hb = (size_t)(n * 16 + h);
    const unsigned short* qg  = Qb  + (hb * 2048 + qt * 64) * 128;
    const unsigned short* kgb = Kb  + hb * 2048 * 128;
    const unsigned short* vgb = Vtb + hb * 128 * 2048;

    // stage Q tile (64x128), swizzled
    {
        int c = tid & 15, rq = tid >> 4;
        #pragma unroll
        for (int i = 0; i < 4; ++i) {
            int row = i * 16 + rq;
            bf16x8 v = *(const bf16x8*)(qg + row * 128 + c * 8);
            *(bf16x8*)&Qs[row * 128 + ((c * 8) ^ ((row & 7) << 3))] = v;
        }
    }
    __syncthreads();

    // hoist Q fragments (constant across KV loop)
    bf16x8 qf[4];
    {
        int qrow = w * 16 + (lane & 15);
        #pragma unroll
        for (int kk = 0; kk < 4; ++kk) {
            int kc = kk * 32 + (lane >> 4) * 8;
            qf[kk] = *(const bf16x8*)&Qs[qrow * 128 + (kc ^ ((qrow & 7) << 3))];
        }
    }

    f32x4 o[8];
    #pragma unroll
    for (int dt = 0; dt < 8; ++dt) { f32x4 z = {0.f,0.f,0.f,0.f}; o[dt] = z; }
    float mstate[4], lstate[4];
    #pragma unroll
    for (int r = 0; r < 4; ++r) { mstate[r] = -INFINITY; lstate[r] = 0.f; }

    const float scale = 0.08838834764831845f;  // 1/sqrt(128)

    for (int kt = 0; kt < 32; ++kt) {
        __syncthreads();   // all waves done reading Ks/Vts of previous tile
        {
            int c = tid & 15, rq = tid >> 4;
            #pragma unroll
            for (int i = 0; i < 4; ++i) {
                int row = i * 16 + rq;
                bf16x8 v = *(const bf16x8*)(kgb + (size_t)(kt * 64 + row) * 128 + c * 8);
                *(bf16x8*)&Ks[row * 128 + ((c * 8) ^ ((row & 7) << 3))] = v;
            }
            int tc = tid & 7, d0 = tid >> 3;
            #pragma unroll
            for (int i = 0; i < 4; ++i) {
                int d = i * 32 + d0;
                bf16x8 v = *(const bf16x8*)(vgb + (size_t)d * 2048 + kt * 64 + tc * 8);
                *(bf16x8*)&Vts[d * 64 + ((tc * 8) ^ ((d & 7) << 3))] = v;
            }
        }
        __syncthreads();

        // scores: S = Q K^T, wave's 16 rows x 64 cols
        f32x4 s[4];
        #pragma unroll
        for (int j = 0; j < 4; ++j) { f32x4 z = {0.f,0.f,0.f,0.f}; s[j] = z; }
        #pragma unroll
        for (int kk = 0; kk < 4; ++kk) {
            int kc = kk * 32 + (lane >> 4) * 8;
            #pragma unroll
            for (int j = 0; j < 4; ++j) {
                int krow = j * 16 + (lane & 15);
                bf16x8 kf = *(const bf16x8*)&Ks[krow * 128 + (kc ^ ((krow & 7) << 3))];
                s[j] = __builtin_amdgcn_mfma_f32_16x16x32_bf16(qf[kk], kf, s[j], 0, 0, 0);
            }
        }

        // online softmax: row r of lane = (lane>>4)*4 + r; 16 lanes share a row
        float sc[4];
        #pragma unroll
        for (int r = 0; r < 4; ++r) {
            float v = fmaxf(fmaxf(s[0][r], s[1][r]), fmaxf(s[2][r], s[3][r])) * scale;
            v = fmaxf(v, __shfl_xor(v, 1));
            v = fmaxf(v, __shfl_xor(v, 2));
            v = fmaxf(v, __shfl_xor(v, 4));
            v = fmaxf(v, __shfl_xor(v, 8));
            float nm = fmaxf(mstate[r], v);
            sc[r] = __expf(mstate[r] - nm);
            mstate[r] = nm;
        }
        float rsum[4] = {0.f, 0.f, 0.f, 0.f};
        #pragma unroll
        for (int j = 0; j < 4; ++j)
            #pragma unroll
            for (int r = 0; r < 4; ++r) {
                float p = __expf(s[j][r] * scale - mstate[r]);
                s[j][r] = p;
                rsum[r] += p;
            }
        #pragma unroll
        for (int r = 0; r < 4; ++r) {
            float t = rsum[r];
            t += __shfl_xor(t, 1);
            t += __shfl_xor(t, 2);
            t += __shfl_xor(t, 4);
            t += __shfl_xor(t, 8);
            lstate[r] = lstate[r] * sc[r] + t;
        }
        #pragma unroll
        for (int dt = 0; dt < 8; ++dt) {
            f32x4 t = o[dt];
            #pragma unroll
            for (int r = 0; r < 4; ++r) t[r] *= sc[r];
            o[dt] = t;
        }

        // write P (bf16) to wave-private LDS stripe, swizzled
        #pragma unroll
        for (int j = 0; j < 4; ++j)
            #pragma unroll
            for (int r = 0; r < 4; ++r) {
                int prow = w * 16 + (lane >> 4) * 4 + r;
                int pcol = j * 16 + (lane & 15);
                Ps[prow * 64 + (pcol ^ ((prow & 7) << 3))] = f2bf(s[j][r]);
            }
        __syncthreads();

        // PV: O += P V  (A = P rows, B = Vt columns-as-rows)
        {
            int prow = w * 16 + (lane & 15);
            #pragma unroll
            for (int kk = 0; kk < 2; ++kk) {
                int kc = kk * 32 + (lane >> 4) * 8;
                bf16x8 pf = *(const bf16x8*)&Ps[prow * 64 + (kc ^ ((prow & 7) << 3))];
                #pragma unroll
                for (int dt = 0; dt < 8; ++dt) {
                    int vrow = dt * 16 + (lane & 15);
                    bf16x8 vf = *(const bf16x8*)&Vts[vrow * 64 + (kc ^ ((vrow & 7) << 3))];
                    o[dt] = __builtin_amdgcn_mfma_f32_16x16x32_bf16(pf, vf, o[dt], 0, 0, 0);
                }
            }
        }
    }

    // epilogue: normalize and store bf16 in (N,H,S,Dk) flat order
    #pragma unroll
    for (int r = 0; r < 4; ++r) {
        float inv = 1.0f / lstate[r];
        int qrow = qt * 64 + w * 16 + (lane >> 4) * 4 + r;
        #pragma unroll
        for (int dt = 0; dt < 8; ++dt) {
            Ob[(hb * 2048 + qrow) * 128 + dt * 16 + (lane & 15)] = f2bf(o[dt][r] * inv);
        }
    }
}

extern "C" void kernel_launch(void* const* d_in, const int* in_sizes, int n_in,
                              void* d_out, int out_size, void* d_ws, size_t ws_size,
                              hipStream_t stream) {
    const float* query = (const float*)d_in[0];
    const float* key   = (const float*)d_in[1];
    const float* value = (const float*)d_in[2];
    const float* Wq    = (const float*)d_in[3];
    const float* bq    = (const float*)d_in[4];
    const float* Wk    = (const float*)d_in[5];
    const float* bk    = (const float*)d_in[6];
    const float* Wv    = (const float*)d_in[7];
    const float* bv    = (const float*)d_in[8];
    const float* Wo    = (const float*)d_in[9];
    const float* bo    = (const float*)d_in[10];

    // ws layout: 4 bf16 buffers of N*S*E = 8388608 elems (16 MiB each, 64 MiB total)
    unsigned short* Qb  = (unsigned short*)d_ws;
    unsigned short* Kb  = Qb  + 8388608;
    unsigned short* Vtb = Kb  + 8388608;
    unsigned short* Ob  = Vtb + 8388608;

    dim3 gg(512), gb(256);
    gemm_bt<float, 0><<<gg, gb, 0, stream>>>(query, Wq, bq, Qb);
    gemm_bt<float, 0><<<gg, gb, 0, stream>>>(key,   Wk, bk, Kb);
    gemm_bt<float, 2><<<gg, gb, 0, stream>>>(value, Wv, bv, Vtb);
    attn_fwd<<<dim3(1024), gb, 0, stream>>>(Qb, Kb, Vtb, Ob);
    gemm_bt<unsigned short, 1><<<gg, gb, 0, stream>>>(Ob, Wo, bo, d_out);
}

// Round 6
// 475.340 us; speedup vs baseline: 1.4974x; 1.4974x over previous
//
#include <hip/hip_runtime.h>

// N=2, S=2048, E=2048, H=16, Dk=128.  M=N*S=4096, K=E=2048.

typedef __attribute__((ext_vector_type(8))) short bf16x8;
typedef __attribute__((ext_vector_type(4))) short bf16x4;
typedef __attribute__((ext_vector_type(4))) float f32x4;

__device__ __forceinline__ unsigned short f2bf(float f) {
    unsigned u = __float_as_uint(f);
    u += 0x7fffu + ((u >> 16) & 1u);   // RNE
    return (unsigned short)(u >> 16);
}

__device__ __forceinline__ void gload_lds16(const unsigned short* g, unsigned short* l) {
    __builtin_amdgcn_global_load_lds(
        (const __attribute__((address_space(1))) unsigned int*)g,
        (__attribute__((address_space(3))) unsigned int*)l, 16, 0, 0);
}

// ---------------------------------------------------------------------------
// fp32 -> bf16 convert, two tensors per launch (c1 may be 0)
// ---------------------------------------------------------------------------
__global__ void cvt2(const float* __restrict__ s0, unsigned short* __restrict__ d0, int c0,
                     const float* __restrict__ s1, unsigned short* __restrict__ d1, int c1)
{
    int total = c0 + c1;
    for (int i = blockIdx.x * blockDim.x + threadIdx.x; i < total; i += gridDim.x * blockDim.x) {
        const float* s; unsigned short* d; int j;
        if (i < c0) { s = s0; d = d0; j = i; } else { s = s1; d = d1; j = i - c0; }
        float4 a = ((const float4*)s)[j * 2];
        float4 b = ((const float4*)s)[j * 2 + 1];
        bf16x8 r;
        r[0] = (short)f2bf(a.x); r[1] = (short)f2bf(a.y);
        r[2] = (short)f2bf(a.z); r[3] = (short)f2bf(a.w);
        r[4] = (short)f2bf(b.x); r[5] = (short)f2bf(b.y);
        r[6] = (short)f2bf(b.z); r[7] = (short)f2bf(b.w);
        ((bf16x8*)d)[j] = r;
    }
}

// ---------------------------------------------------------------------------
// GEMM: C[m][j] = (sum_k A[m][k]*B[j][k] + bias[j]) * cscale
// A: 4096x2048 bf16, B: 2048x2048 bf16 (row-major, B^T gemm).
// MODE 0: bf16 head-split [n][h][s][d]; MODE 2: bf16 [n][h][d][s]; MODE 1: fp32 flat.
// 128x128 tile, BK=64, 4 waves, double-buffered LDS, global_load_lds staging
// with pre-swizzled source (chunk ^= row&7), one barrier per K-step.
// ---------------------------------------------------------------------------
template<int MODE>
__global__ __launch_bounds__(256, 2) void gemm_bt2(
    const unsigned short* __restrict__ A, const unsigned short* __restrict__ B,
    const float* __restrict__ bias, void* __restrict__ Cout, float cscale)
{
    const int K = 2048;
    __shared__ __align__(16) unsigned short SM[32768];   // 2 x (As 8192 + Bs 8192)

    const int tid  = threadIdx.x;
    const int lane = tid & 63;
    const int w    = tid >> 6;
    const int wr   = w >> 1, wc = w & 1;

    int bid = blockIdx.x;
    int bl  = (bid & 7) * 64 + (bid >> 3);     // XCD swizzle, 512 = 8*64 bijective
    const int m0 = (bl & 31) << 7;
    const int n0 = (bl >> 5) << 7;

    const int lr8 = lane >> 3;                 // row within 8-row chunk
    const int sc8 = (lane & 7) ^ lr8;          // pre-swizzled source chunk

    f32x4 acc[4][4];
    #pragma unroll
    for (int i = 0; i < 4; ++i)
        #pragma unroll
        for (int j = 0; j < 4; ++j) { f32x4 z = {0.f,0.f,0.f,0.f}; acc[i][j] = z; }

    auto stage = [&](int kt, unsigned short* As_, unsigned short* Bs_) {
        const int k0 = kt * 64;
        #pragma unroll
        for (int i = 0; i < 4; ++i) {
            int row = w * 32 + i * 8 + lr8;    // row&7 == lr8
            gload_lds16(A + (size_t)(m0 + row) * K + k0 + sc8 * 8, As_ + (w * 4 + i) * 512);
            gload_lds16(B + (size_t)(n0 + row) * K + k0 + sc8 * 8, Bs_ + (w * 4 + i) * 512);
        }
    };

    stage(0, SM, SM + 8192);
    __syncthreads();

    int cur = 0;
    for (int kt = 0; kt < 32; ++kt) {
        unsigned short* As_ = SM + (cur ? 16384 : 0);
        unsigned short* Bs_ = As_ + 8192;
        if (kt < 31) stage(kt + 1, SM + (cur ? 0 : 16384), SM + (cur ? 8192 : 24576));

        #pragma unroll
        for (int kk = 0; kk < 2; ++kk) {
            const int kc = kk * 32 + (lane >> 4) * 8;
            bf16x8 af[4], bfr[4];
            #pragma unroll
            for (int t = 0; t < 4; ++t) {
                int ar = wr * 64 + t * 16 + (lane & 15);
                af[t]  = *(const bf16x8*)&As_[ar * 64 + (kc ^ ((ar & 7) << 3))];
                int br = wc * 64 + t * 16 + (lane & 15);
                bfr[t] = *(const bf16x8*)&Bs_[br * 64 + (kc ^ ((br & 7) << 3))];
            }
            #pragma unroll
            for (int tm = 0; tm < 4; ++tm)
                #pragma unroll
                for (int tn = 0; tn < 4; ++tn)
                    acc[tm][tn] = __builtin_amdgcn_mfma_f32_16x16x32_bf16(
                        af[tm], bfr[tn], acc[tm][tn], 0, 0, 0);
        }
        __syncthreads();
        cur ^= 1;
    }

    // epilogue: C/D layout col=lane&15, row=(lane>>4)*4+reg
    const int lr = lane >> 4, lc = lane & 15;
    #pragma unroll
    for (int tn = 0; tn < 4; ++tn) {
        int col = n0 + wc * 64 + tn * 16 + lc;
        float bv = bias[col];
        #pragma unroll
        for (int tm = 0; tm < 4; ++tm) {
            int row0 = m0 + wr * 64 + tm * 16 + lr * 4;
            if constexpr (MODE == 1) {
                #pragma unroll
                for (int r = 0; r < 4; ++r)
                    ((float*)Cout)[(size_t)(row0 + r) * 2048 + col] = acc[tm][tn][r] + bv;
            } else if constexpr (MODE == 0) {
                #pragma unroll
                for (int r = 0; r < 4; ++r) {
                    int row = row0 + r;
                    int nb = row >> 11, s = row & 2047, h = col >> 7, d = col & 127;
                    ((unsigned short*)Cout)[(((size_t)(nb * 16 + h)) * 2048 + s) * 128 + d] =
                        f2bf((acc[tm][tn][r] + bv) * cscale);
                }
            } else {  // MODE 2: [n][h][d][s], pack 4 consecutive s
                int nb = row0 >> 11, s0 = row0 & 2047, h = col >> 7, d = col & 127;
                bf16x4 pk;
                #pragma unroll
                for (int r = 0; r < 4; ++r) pk[r] = (short)f2bf(acc[tm][tn][r] + bv);
                *(bf16x4*)&((unsigned short*)Cout)[(((size_t)(nb * 16 + h)) * 128 + d) * 2048 + s0] = pk;
            }
        }
    }
}

// ---------------------------------------------------------------------------
// Flash attention v2. Grid 512: 32 (n,h) x 16 qtiles, QBLK=128.
// 4 waves; wave w owns rows w*32..w*32+31 (2 rowgroups of 16).
// K/V double-buffered via global_load_lds (pre-swizzled source), 1 barrier/kt.
// Q pre-scaled by 1/sqrt(Dk) at projection.
// ---------------------------------------------------------------------------
__global__ __launch_bounds__(256, 2) void attn_fwd2(
    const unsigned short* __restrict__ Qb, const unsigned short* __restrict__ Kb,
    const unsigned short* __restrict__ Vtb, unsigned short* __restrict__ Ob)
{
    __shared__ __align__(16) unsigned short SM[40960];  // buf0 K|V (16384), buf1 K|V (16384), Ps (8192)
    unsigned short* Ps     = SM + 32768;
    unsigned short* Qstage = SM + 16384;                // overlaps buf1 during prologue

    const int tid = threadIdx.x, lane = tid & 63, w = tid >> 6;
    int bid = blockIdx.x;
    int bl  = (bid & 7) * 64 + (bid >> 3);              // 4 heads per XCD
    const int qt = bl & 15;
    const int hb = bl >> 4;                             // 0..31

    const unsigned short* qg  = Qb  + ((size_t)hb * 2048 + qt * 128) * 128;
    const unsigned short* kgb = Kb  + (size_t)hb * 2048 * 128;
    const unsigned short* vgb = Vtb + (size_t)hb * 128 * 2048;

    const int lK_r = lane >> 4, lK_c = lane & 15;       // K: 4 rows/chunk of 256B
    const int lV_r = lane >> 3, lV_c = lane & 7;        // V: 8 rows/chunk of 128B

    auto stageKV = [&](int kt, unsigned short* Kc, unsigned short* Vc) {
        #pragma unroll
        for (int i = 0; i < 4; ++i) {
            int ci = w * 4 + i;
            int krow = ci * 4 + lK_r;
            int ksrc = lK_c ^ (krow & 7);
            gload_lds16(kgb + (size_t)(kt * 64 + krow) * 128 + ksrc * 8, Kc + ci * 512);
            int vrow = ci * 8 + lV_r;
            int vsrc = lV_c ^ (vrow & 7);
            gload_lds16(vgb + (size_t)vrow * 2048 + kt * 64 + vsrc * 8, Vc + ci * 512);
        }
    };

    // prologue: Q -> Qstage (reg-staged, swizzled), KV tile0 -> buf0 (async)
    {
        int c = tid & 15, rq = tid >> 4;
        #pragma unroll
        for (int i = 0; i < 8; ++i) {
            int row = i * 16 + rq;
            bf16x8 v = *(const bf16x8*)(qg + row * 128 + c * 8);
            *(bf16x8*)&Qstage[row * 128 + ((c * 8) ^ ((row & 7) << 3))] = v;
        }
    }
    stageKV(0, SM, SM + 8192);
    __syncthreads();

    bf16x8 qf[2][4];
    #pragma unroll
    for (int rg = 0; rg < 2; ++rg) {
        int qrow = w * 32 + rg * 16 + (lane & 15);
        #pragma unroll
        for (int kk = 0; kk < 4; ++kk) {
            int kc = kk * 32 + (lane >> 4) * 8;
            qf[rg][kk] = *(const bf16x8*)&Qstage[qrow * 128 + (kc ^ ((qrow & 7) << 3))];
        }
    }
    __syncthreads();   // hoist done before buf1 (Qstage) is overwritten

    f32x4 o[2][8];
    #pragma unroll
    for (int rg = 0; rg < 2; ++rg)
        #pragma unroll
        for (int dt = 0; dt < 8; ++dt) { f32x4 z = {0.f,0.f,0.f,0.f}; o[rg][dt] = z; }
    float mstate[2][4], lstate[2][4];
    #pragma unroll
    for (int rg = 0; rg < 2; ++rg)
        #pragma unroll
        for (int r = 0; r < 4; ++r) { mstate[rg][r] = -INFINITY; lstate[rg][r] = 0.f; }

    int cur = 0;
    for (int kt = 0; kt < 32; ++kt) {
        unsigned short* Kc = SM + (cur ? 16384 : 0);
        unsigned short* Vc = Kc + 8192;
        if (kt < 31) stageKV(kt + 1, SM + (cur ? 0 : 16384), SM + (cur ? 8192 : 24576));

        // QK^T
        f32x4 s[2][4];
        #pragma unroll
        for (int rg = 0; rg < 2; ++rg)
            #pragma unroll
            for (int j = 0; j < 4; ++j) { f32x4 z = {0.f,0.f,0.f,0.f}; s[rg][j] = z; }
        __builtin_amdgcn_s_setprio(1);
        #pragma unroll
        for (int kk = 0; kk < 4; ++kk) {
            int kc = kk * 32 + (lane >> 4) * 8;
            #pragma unroll
            for (int j = 0; j < 4; ++j) {
                int krow = j * 16 + (lane & 15);
                bf16x8 kf = *(const bf16x8*)&Kc[krow * 128 + (kc ^ ((krow & 7) << 3))];
                s[0][j] = __builtin_amdgcn_mfma_f32_16x16x32_bf16(qf[0][kk], kf, s[0][j], 0, 0, 0);
                s[1][j] = __builtin_amdgcn_mfma_f32_16x16x32_bf16(qf[1][kk], kf, s[1][j], 0, 0, 0);
            }
        }
        __builtin_amdgcn_s_setprio(0);

        // online softmax per rowgroup (defer-max THR=8)
        #pragma unroll
        for (int rg = 0; rg < 2; ++rg) {
            float pmax[4];
            #pragma unroll
            for (int r = 0; r < 4; ++r) {
                float v = fmaxf(fmaxf(s[rg][0][r], s[rg][1][r]), fmaxf(s[rg][2][r], s[rg][3][r]));
                v = fmaxf(v, __shfl_xor(v, 1));
                v = fmaxf(v, __shfl_xor(v, 2));
                v = fmaxf(v, __shfl_xor(v, 4));
                v = fmaxf(v, __shfl_xor(v, 8));
                pmax[r] = v;
            }
            bool need = false;
            #pragma unroll
            for (int r = 0; r < 4; ++r) need |= (pmax[r] - mstate[rg][r] > 8.0f);
            if (__any(need)) {
                #pragma unroll
                for (int r = 0; r < 4; ++r) {
                    float nm = fmaxf(mstate[rg][r], pmax[r]);
                    float sc = __expf(mstate[rg][r] - nm);
                    mstate[rg][r] = nm;
                    lstate[rg][r] *= sc;
                    #pragma unroll
                    for (int dt = 0; dt < 8; ++dt) o[rg][dt][r] *= sc;
                }
            }
            float rsum[4] = {0.f, 0.f, 0.f, 0.f};
            #pragma unroll
            for (int j = 0; j < 4; ++j)
                #pragma unroll
                for (int r = 0; r < 4; ++r) {
                    float p = __expf(s[rg][j][r] - mstate[rg][r]);
                    s[rg][j][r] = p;
                    rsum[r] += p;
                }
            #pragma unroll
            for (int r = 0; r < 4; ++r) {
                float t = rsum[r];
                t += __shfl_xor(t, 1);
                t += __shfl_xor(t, 2);
                t += __shfl_xor(t, 4);
                t += __shfl_xor(t, 8);
                lstate[rg][r] += t;
            }
            #pragma unroll
            for (int j = 0; j < 4; ++j)
                #pragma unroll
                for (int r = 0; r < 4; ++r) {
                    int prow = w * 32 + rg * 16 + (lane >> 4) * 4 + r;
                    int pcol = j * 16 + (lane & 15);
                    Ps[prow * 64 + (pcol ^ ((prow & 7) << 3))] = f2bf(s[rg][j][r]);
                }
        }

        // PV (Ps is wave-private: no barrier needed)
        __builtin_amdgcn_s_setprio(1);
        #pragma unroll
        for (int kk = 0; kk < 2; ++kk) {
            int kc = kk * 32 + (lane >> 4) * 8;
            int pr0 = w * 32 + (lane & 15);
            bf16x8 pf0 = *(const bf16x8*)&Ps[pr0 * 64 + (kc ^ ((pr0 & 7) << 3))];
            int pr1 = pr0 + 16;
            bf16x8 pf1 = *(const bf16x8*)&Ps[pr1 * 64 + (kc ^ ((pr1 & 7) << 3))];
            #pragma unroll
            for (int dt = 0; dt < 8; ++dt) {
                int vrow = dt * 16 + (lane & 15);
                bf16x8 vf = *(const bf16x8*)&Vc[vrow * 64 + (kc ^ ((vrow & 7) << 3))];
                o[0][dt] = __builtin_amdgcn_mfma_f32_16x16x32_bf16(pf0, vf, o[0][dt], 0, 0, 0);
                o[1][dt] = __builtin_amdgcn_mfma_f32_16x16x32_bf16(pf1, vf, o[1][dt], 0, 0, 0);
            }
        }
        __builtin_amdgcn_s_setprio(0);

        __syncthreads();
        cur ^= 1;
    }

    // epilogue: normalize, store bf16 (N,H,S,Dk)
    #pragma unroll
    for (int rg = 0; rg < 2; ++rg)
        #pragma unroll
        for (int r = 0; r < 4; ++r) {
            float inv = 1.0f / lstate[rg][r];
            int qrow = qt * 128 + w * 32 + rg * 16 + (lane >> 4) * 4 + r;
            #pragma unroll
            for (int dt = 0; dt < 8; ++dt)
                Ob[((size_t)hb * 2048 + qrow) * 128 + dt * 16 + (lane & 15)] = f2bf(o[rg][dt][r] * inv);
        }
}

extern "C" void kernel_launch(void* const* d_in, const int* in_sizes, int n_in,
                              void* d_out, int out_size, void* d_ws, size_t ws_size,
                              hipStream_t stream) {
    const float* query = (const float*)d_in[0];
    const float* key   = (const float*)d_in[1];
    const float* value = (const float*)d_in[2];
    const float* Wq    = (const float*)d_in[3];
    const float* bq    = (const float*)d_in[4];
    const float* Wk    = (const float*)d_in[5];
    const float* bk    = (const float*)d_in[6];
    const float* Wv    = (const float*)d_in[7];
    const float* bv    = (const float*)d_in[8];
    const float* Wo    = (const float*)d_in[9];
    const float* bo    = (const float*)d_in[10];

    // ws (64 MiB, proven): Qb | Kb | Vtb | Xslot (Xv/Xq/Xk then Ob)
    unsigned short* Qb  = (unsigned short*)d_ws;
    unsigned short* Kb  = Qb  + 8388608;
    unsigned short* Vtb = Kb  + 8388608;
    unsigned short* Xs  = Vtb + 8388608;
    // rotating bf16 weight slot in d_out's first 8 MB (overwritten by final GEMM)
    unsigned short* Wsl = (unsigned short*)d_out;
    // Wo slot: Qb region (dead after attention)
    unsigned short* Wos = Qb;

    const int CX = 1048576;   // 8388608/8
    const int CW = 524288;    // 4194304/8
    const float qscale = 0.08838834764831845f;  // 1/sqrt(128)

    dim3 B(256);
    // V projection first (its weight slot lives in d_out)
    cvt2<<<dim3(1024), B, 0, stream>>>(value, Xs, CX, Wv, Wsl, CW);
    gemm_bt2<2><<<dim3(512), B, 0, stream>>>(Xs, Wsl, bv, Vtb, 1.0f);
    cvt2<<<dim3(1024), B, 0, stream>>>(query, Xs, CX, Wq, Wsl, CW);
    gemm_bt2<0><<<dim3(512), B, 0, stream>>>(Xs, Wsl, bq, Qb, qscale);
    cvt2<<<dim3(1024), B, 0, stream>>>(key, Xs, CX, Wk, Wsl, CW);
    gemm_bt2<0><<<dim3(512), B, 0, stream>>>(Xs, Wsl, bk, Kb, 1.0f);
    // attention: Ob -> Xs (Xk dead)
    attn_fwd2<<<dim3(512), B, 0, stream>>>(Qb, Kb, Vtb, Xs);
    // Wo -> Qb region (dead), then output GEMM -> d_out (overwrites Wsl region)
    cvt2<<<dim3(512), B, 0, stream>>>(Wo, Wos, CW, Wo, Wos, 0);
    gemm_bt2<1><<<dim3(512), B, 0, stream>>>(Xs, Wos, bo, d_out, 1.0f);
}

// Round 8
// 456.264 us; speedup vs baseline: 1.5600x; 1.0418x over previous
//
#include <hip/hip_runtime.h>

// N=2, S=2048, E=2048, H=16, Dk=128.  M=N*S=4096, K=E=2048.

typedef __attribute__((ext_vector_type(8))) short bf16x8;
typedef __attribute__((ext_vector_type(4))) short bf16x4;
typedef __attribute__((ext_vector_type(4))) float f32x4;
typedef __attribute__((ext_vector_type(16))) float f32x16;
typedef unsigned int u32;

__device__ __forceinline__ unsigned short f2bf(float f) {
    unsigned u = __float_as_uint(f);
    u += 0x7fffu + ((u >> 16) & 1u);   // RNE
    return (unsigned short)(u >> 16);
}

__device__ __forceinline__ u32 pack2bf(float lo, float hi) {
    return (u32)f2bf(lo) | ((u32)f2bf(hi) << 16);
}

__device__ __forceinline__ void gload_lds16(const unsigned short* g, unsigned short* l) {
    __builtin_amdgcn_global_load_lds(
        (const __attribute__((address_space(1))) unsigned int*)g,
        (__attribute__((address_space(3))) unsigned int*)l, 16, 0, 0);
}

// ---------------------------------------------------------------------------
// fp32 -> bf16 convert, two tensors per launch (c1 may be 0)
// ---------------------------------------------------------------------------
__global__ void cvt2(const float* __restrict__ s0, unsigned short* __restrict__ d0, int c0,
                     const float* __restrict__ s1, unsigned short* __restrict__ d1, int c1)
{
    int total = c0 + c1;
    for (int i = blockIdx.x * blockDim.x + threadIdx.x; i < total; i += gridDim.x * blockDim.x) {
        const float* s; unsigned short* d; int j;
        if (i < c0) { s = s0; d = d0; j = i; } else { s = s1; d = d1; j = i - c0; }
        float4 a = ((const float4*)s)[j * 2];
        float4 b = ((const float4*)s)[j * 2 + 1];
        bf16x8 r;
        r[0] = (short)f2bf(a.x); r[1] = (short)f2bf(a.y);
        r[2] = (short)f2bf(a.z); r[3] = (short)f2bf(a.w);
        r[4] = (short)f2bf(b.x); r[5] = (short)f2bf(b.y);
        r[6] = (short)f2bf(b.z); r[7] = (short)f2bf(b.w);
        ((bf16x8*)d)[j] = r;
    }
}

// ---------------------------------------------------------------------------
// GEMM (unchanged from round 6, proven): C[m][j] = (sum_k A[m][k]*B[j][k] + bias[j]) * cscale
// ---------------------------------------------------------------------------
template<int MODE>
__global__ __launch_bounds__(256, 2) void gemm_bt2(
    const unsigned short* __restrict__ A, const unsigned short* __restrict__ B,
    const float* __restrict__ bias, void* __restrict__ Cout, float cscale)
{
    const int K = 2048;
    __shared__ __align__(16) unsigned short SM[32768];

    const int tid  = threadIdx.x;
    const int lane = tid & 63;
    const int w    = tid >> 6;
    const int wr   = w >> 1, wc = w & 1;

    int bid = blockIdx.x;
    int bl  = (bid & 7) * 64 + (bid >> 3);
    const int m0 = (bl & 31) << 7;
    const int n0 = (bl >> 5) << 7;

    const int lr8 = lane >> 3;
    const int sc8 = (lane & 7) ^ lr8;

    f32x4 acc[4][4];
    #pragma unroll
    for (int i = 0; i < 4; ++i)
        #pragma unroll
        for (int j = 0; j < 4; ++j) { f32x4 z = {0.f,0.f,0.f,0.f}; acc[i][j] = z; }

    auto stage = [&](int kt, unsigned short* As_, unsigned short* Bs_) {
        const int k0 = kt * 64;
        #pragma unroll
        for (int i = 0; i < 4; ++i) {
            int row = w * 32 + i * 8 + lr8;
            gload_lds16(A + (size_t)(m0 + row) * K + k0 + sc8 * 8, As_ + (w * 4 + i) * 512);
            gload_lds16(B + (size_t)(n0 + row) * K + k0 + sc8 * 8, Bs_ + (w * 4 + i) * 512);
        }
    };

    stage(0, SM, SM + 8192);
    __syncthreads();

    int cur = 0;
    for (int kt = 0; kt < 32; ++kt) {
        unsigned short* As_ = SM + (cur ? 16384 : 0);
        unsigned short* Bs_ = As_ + 8192;
        if (kt < 31) stage(kt + 1, SM + (cur ? 0 : 16384), SM + (cur ? 8192 : 24576));

        #pragma unroll
        for (int kk = 0; kk < 2; ++kk) {
            const int kc = kk * 32 + (lane >> 4) * 8;
            bf16x8 af[4], bfr[4];
            #pragma unroll
            for (int t = 0; t < 4; ++t) {
                int ar = wr * 64 + t * 16 + (lane & 15);
                af[t]  = *(const bf16x8*)&As_[ar * 64 + (kc ^ ((ar & 7) << 3))];
                int br = wc * 64 + t * 16 + (lane & 15);
                bfr[t] = *(const bf16x8*)&Bs_[br * 64 + (kc ^ ((br & 7) << 3))];
            }
            #pragma unroll
            for (int tm = 0; tm < 4; ++tm)
                #pragma unroll
                for (int tn = 0; tn < 4; ++tn)
                    acc[tm][tn] = __builtin_amdgcn_mfma_f32_16x16x32_bf16(
                        af[tm], bfr[tn], acc[tm][tn], 0, 0, 0);
        }
        __syncthreads();
        cur ^= 1;
    }

    const int lr = lane >> 4, lc = lane & 15;
    #pragma unroll
    for (int tn = 0; tn < 4; ++tn) {
        int col = n0 + wc * 64 + tn * 16 + lc;
        float bv = bias[col];
        #pragma unroll
        for (int tm = 0; tm < 4; ++tm) {
            int row0 = m0 + wr * 64 + tm * 16 + lr * 4;
            if constexpr (MODE == 1) {
                #pragma unroll
                for (int r = 0; r < 4; ++r)
                    ((float*)Cout)[(size_t)(row0 + r) * 2048 + col] = acc[tm][tn][r] + bv;
            } else if constexpr (MODE == 0) {
                #pragma unroll
                for (int r = 0; r < 4; ++r) {
                    int row = row0 + r;
                    int nb = row >> 11, s = row & 2047, h = col >> 7, d = col & 127;
                    ((unsigned short*)Cout)[(((size_t)(nb * 16 + h)) * 2048 + s) * 128 + d] =
                        f2bf((acc[tm][tn][r] + bv) * cscale);
                }
            } else {
                int nb = row0 >> 11, s0 = row0 & 2047, h = col >> 7, d = col & 127;
                bf16x4 pk;
                #pragma unroll
                for (int r = 0; r < 4; ++r) pk[r] = (short)f2bf(acc[tm][tn][r] + bv);
                *(bf16x4*)&((unsigned short*)Cout)[(((size_t)(nb * 16 + h)) * 128 + d) * 2048 + s0] = pk;
            }
        }
    }
}

// ---------------------------------------------------------------------------
// Flash attention v3: 8 warps x 32 q-rows (Q-block 256), KVBLK=64, 32x32x16 MFMA,
// swapped QK^T (S^T = K Q^T) -> P lane-local -> in-register softmax (log2 domain,
// qscale includes log2e) -> pack+2xshfl -> PV as O^T = V^T P^T (stats lane-local).
// K LDS 4-bit chunk XOR swizzle; V 3-bit. Double-buffered global_load_lds staging.
// Grid 256 = 32 (n,h) x 8 qtiles, XCD-swizzled. 512 threads.
// ---------------------------------------------------------------------------
__global__ __launch_bounds__(512, 2) void attn_fwd3(
    const unsigned short* __restrict__ Qb, const unsigned short* __restrict__ Kb,
    const unsigned short* __restrict__ Vtb, unsigned short* __restrict__ Ob)
{
    __shared__ __align__(16) unsigned short SM[32768];  // 2 x (K 8192 | V 8192)

    const int tid = threadIdx.x, lane = tid & 63, w = tid >> 6;
    const int l31 = lane & 31, h = lane >> 5;

    int bid = blockIdx.x;
    int bl  = (bid & 7) * 32 + (bid >> 3);   // 256 = 8*32 bijective; 4 heads/XCD
    const int qt = bl & 7;
    const int hb = bl >> 3;                  // 0..31

    const unsigned short* qg  = Qb  + ((size_t)hb * 2048 + qt * 256) * 128;
    const unsigned short* kgb = Kb  + (size_t)hb * 2048 * 128;
    const unsigned short* vgb = Vtb + (size_t)hb * 128 * 2048;

    auto stage = [&](int kt, int c) {
        unsigned short* Kl = SM + c * 16384;
        unsigned short* Vl = Kl + 8192;
        #pragma unroll
        for (int i = 0; i < 2; ++i) {
            int ck = tid + i * 512;          // K: 1024 chunks, 16/row (4-bit swz)
            int kr = ck >> 4, kc = (ck & 15) ^ (kr & 15);
            gload_lds16(kgb + (size_t)(kt * 64 + kr) * 128 + kc * 8, Kl + ck * 8);
            int cv = tid + i * 512;          // V: 1024 chunks, 8/row (3-bit swz)
            int vr = cv >> 3, vc = (cv & 7) ^ (vr & 7);
            gload_lds16(vgb + (size_t)vr * 2048 + kt * 64 + vc * 8, Vl + cv * 8);
        }
    };

    // Q fragments: q = lane&31 (B-operand col), d = ds*16 + 8h + e
    bf16x8 qf[8];
    const int qrow = qt * 256 + w * 32 + l31;
    {
        const unsigned short* qp = Qb + ((size_t)hb * 2048 + qrow) * 128 + h * 8;
        #pragma unroll
        for (int ds = 0; ds < 8; ++ds)
            qf[ds] = *(const bf16x8*)(qp + ds * 16);
    }
    (void)qg;

    stage(0, 0);

    f32x16 o[4];
    #pragma unroll
    for (int d = 0; d < 4; ++d)
        #pragma unroll
        for (int r = 0; r < 16; ++r) o[d][r] = 0.f;
    float m_ = -INFINITY, l_ = 0.f;

    __syncthreads();

    for (int kt = 0; kt < 32; ++kt) {
        int cur = kt & 1;
        if (kt < 31) stage(kt + 1, cur ^ 1);
        unsigned short* Kl = SM + cur * 16384;
        unsigned short* Vl = Kl + 8192;

        // QK^T: S^T[k][q], two 32-k blocks. A=K rows (row=l31), B=Q (col=l31).
        f32x16 sA, sB;
        #pragma unroll
        for (int r = 0; r < 16; ++r) { sA[r] = 0.f; sB[r] = 0.f; }
        __builtin_amdgcn_s_setprio(1);
        #pragma unroll
        for (int ds = 0; ds < 8; ++ds) {
            int ch = ds * 2 + h;
            int sw = (ch ^ (l31 & 15)) << 3;           // rows r and r+32 share l31&15
            bf16x8 k0 = *(const bf16x8*)&Kl[l31 * 128 + sw];
            bf16x8 k1 = *(const bf16x8*)&Kl[(32 + l31) * 128 + sw];
            sA = __builtin_amdgcn_mfma_f32_32x32x16_bf16(k0, qf[ds], sA, 0, 0, 0);
            sB = __builtin_amdgcn_mfma_f32_32x32x16_bf16(k1, qf[ds], sB, 0, 0, 0);
        }
        __builtin_amdgcn_s_setprio(0);

        // row max (lane-local 32 values + one cross-half swap)
        float mx[16];
        #pragma unroll
        for (int r = 0; r < 16; ++r) mx[r] = fmaxf(sA[r], sB[r]);
        #pragma unroll
        for (int st = 8; st > 0; st >>= 1)
            #pragma unroll
            for (int r = 0; r < st; ++r) mx[r] = fmaxf(mx[r], mx[r + st]);
        float pmax = fmaxf(mx[0], __shfl_xor(mx[0], 32));

        // defer-max rescale (log2 domain; P <= 2^8)
        if (__any(pmax - m_ > 8.0f)) {
            float nm = fmaxf(m_, pmax);
            float sc = exp2f(m_ - nm);
            m_ = nm; l_ *= sc;
            #pragma unroll
            for (int d = 0; d < 4; ++d)
                #pragma unroll
                for (int r = 0; r < 16; ++r) o[d][r] *= sc;
        }

        // P = 2^(s - m)
        float p[32];
        float sm[16];
        #pragma unroll
        for (int r = 0; r < 16; ++r) {
            p[r]      = exp2f(sA[r] - m_);
            p[16 + r] = exp2f(sB[r] - m_);
            sm[r] = p[r] + p[16 + r];
        }
        #pragma unroll
        for (int st = 8; st > 0; st >>= 1)
            #pragma unroll
            for (int r = 0; r < st; ++r) sm[r] += sm[r + st];
        l_ += sm[0] + __shfl_xor(sm[0], 32);

        // pack P into PV operand fragments: pa[ks] covers k = ks*16 + 8h + e
        u32 paw[4][4];
        #pragma unroll
        for (int kb = 0; kb < 2; ++kb) {
            #pragma unroll
            for (int sg = 0; sg < 2; ++sg) {
                const int b = kb * 16 + 8 * sg;
                u32 w0 = pack2bf(p[b + 0], p[b + 1]);
                u32 w1 = pack2bf(p[b + 2], p[b + 3]);
                u32 w2 = pack2bf(p[b + 4], p[b + 5]);
                u32 w3 = pack2bf(p[b + 6], p[b + 7]);
                u32 s0 = h ? w0 : w2, s1 = h ? w1 : w3;
                u32 r0 = __shfl_xor(s0, 32), r1 = __shfl_xor(s1, 32);
                int ks = kb * 2 + sg;
                paw[ks][0] = h ? r0 : w0;
                paw[ks][1] = h ? r1 : w1;
                paw[ks][2] = h ? w2 : r0;
                paw[ks][3] = h ? w3 : r1;
            }
        }

        // PV: O^T[d][q] += V^T[d][k] P^T[k][q]; A=V^T rows (row=l31), B=pa (col=l31)
        __builtin_amdgcn_s_setprio(1);
        #pragma unroll
        for (int ks = 0; ks < 4; ++ks) {
            union { u32 u[4]; bf16x8 v; } pu;
            pu.u[0] = paw[ks][0]; pu.u[1] = paw[ks][1];
            pu.u[2] = paw[ks][2]; pu.u[3] = paw[ks][3];
            bf16x8 pa = pu.v;
            int ch = ks * 2 + h;
            #pragma unroll
            for (int db = 0; db < 4; ++db) {
                int vr = db * 32 + l31;
                bf16x8 vf = *(const bf16x8*)&Vl[vr * 64 + ((ch ^ (vr & 7)) << 3)];
                o[db] = __builtin_amdgcn_mfma_f32_32x32x16_bf16(vf, pa, o[db], 0, 0, 0);
            }
        }
        __builtin_amdgcn_s_setprio(0);

        __syncthreads();
    }

    // epilogue: lane holds O^T: q = l31, d = db*32 + (reg&3) + 8*(reg>>2) + 4h
    float inv = 1.0f / l_;
    unsigned short* op = Ob + ((size_t)hb * 2048 + qrow) * 128;
    #pragma unroll
    for (int db = 0; db < 4; ++db) {
        #pragma unroll
        for (int g = 0; g < 4; ++g) {
            bf16x4 pk;
            #pragma unroll
            for (int j = 0; j < 4; ++j) pk[j] = (short)f2bf(o[db][g * 4 + j] * inv);
            *(bf16x4*)&op[db * 32 + 8 * g + 4 * h] = pk;
        }
    }
}

extern "C" void kernel_launch(void* const* d_in, const int* in_sizes, int n_in,
                              void* d_out, int out_size, void* d_ws, size_t ws_size,
                              hipStream_t stream) {
    const float* query = (const float*)d_in[0];
    const float* key   = (const float*)d_in[1];
    const float* value = (const float*)d_in[2];
    const float* Wq    = (const float*)d_in[3];
    const float* bq    = (const float*)d_in[4];
    const float* Wk    = (const float*)d_in[5];
    const float* bk    = (const float*)d_in[6];
    const float* Wv    = (const float*)d_in[7];
    const float* bv    = (const float*)d_in[8];
    const float* Wo    = (const float*)d_in[9];
    const float* bo    = (const float*)d_in[10];

    unsigned short* Qb  = (unsigned short*)d_ws;
    unsigned short* Kb  = Qb  + 8388608;
    unsigned short* Vtb = Kb  + 8388608;
    unsigned short* Xs  = Vtb + 8388608;
    unsigned short* Wsl = (unsigned short*)d_out;
    unsigned short* Wos = Qb;

    const int CX = 1048576;
    const int CW = 524288;
    // 1/sqrt(128) * log2(e): attention softmax runs in log2 domain (exp2f)
    const float qscale = 0.08838834764831845f * 1.4426950408889634f;

    dim3 B(256);
    cvt2<<<dim3(1024), B, 0, stream>>>(value, Xs, CX, Wv, Wsl, CW);
    gemm_bt2<2><<<dim3(512), B, 0, stream>>>(Xs, Wsl, bv, Vtb, 1.0f);
    cvt2<<<dim3(1024), B, 0, stream>>>(query, Xs, CX, Wq, Wsl, CW);
    gemm_bt2<0><<<dim3(512), B, 0, stream>>>(Xs, Wsl, bq, Qb, qscale);
    cvt2<<<dim3(1024), B, 0, stream>>>(key, Xs, CX, Wk, Wsl, CW);
    gemm_bt2<0><<<dim3(512), B, 0, stream>>>(Xs, Wsl, bk, Kb, 1.0f);
    attn_fwd3<<<dim3(256), dim3(512), 0, stream>>>(Qb, Kb, Vtb, Xs);
    cvt2<<<dim3(512), B, 0, stream>>>(Wo, Wos, CW, Wo, Wos, 0);
    gemm_bt2<1><<<dim3(512), B, 0, stream>>>(Xs, Wos, bo, d_out, 1.0f);
}